// Round 1
// baseline (1078.630 us; speedup 1.0000x reference)
//
#include <hip/hip_runtime.h>
#include <hip/hip_bf16.h>

#define NTOK 4096
#define DDIM 1024
#define HDIM 4096
#define NEXP 8
#define TM 128
#define TN 128
#define BK 64
#define LDP 72   // padded LDS row length (elements): 144B rows -> 2-way bank alias (free)

typedef __attribute__((ext_vector_type(4))) float f32x4;
typedef __attribute__((ext_vector_type(8))) short bf16x8;
typedef __attribute__((ext_vector_type(4))) short bf16x4;

static __device__ __forceinline__ short f2bf(float f) {
  union { __hip_bfloat16 b; short s; } u;
  u.b = __float2bfloat16(f);
  return u.s;
}

// ---------------- Router: one wave per token ----------------
__global__ __launch_bounds__(256) void router_kernel(
    const float* __restrict__ x, const float* __restrict__ gw,
    const float* __restrict__ rs,
    int* __restrict__ tok_id, float* __restrict__ tok_w,
    int* __restrict__ counts)
{
  const int wv = threadIdx.x >> 6;
  const int lane = threadIdx.x & 63;
  const int tok = blockIdx.x * 4 + wv;
  const f32x4* xr = (const f32x4*)(x + (size_t)tok * DDIM);
  f32x4 xv[4];
#pragma unroll
  for (int j = 0; j < 4; ++j) xv[j] = xr[j * 64 + lane];
  float lg[NEXP];
#pragma unroll
  for (int e = 0; e < NEXP; ++e) {
    const f32x4* gr = (const f32x4*)(gw + (size_t)e * DDIM);
    float s = 0.f;
#pragma unroll
    for (int j = 0; j < 4; ++j) {
      f32x4 g = gr[j * 64 + lane];
      s += g[0]*xv[j][0] + g[1]*xv[j][1] + g[2]*xv[j][2] + g[3]*xv[j][3];
    }
#pragma unroll
    for (int off = 32; off > 0; off >>= 1) s += __shfl_down(s, off, 64);
    lg[e] = s;
  }
  if (lane == 0) {
    const float scale = rs[0];
#pragma unroll
    for (int e = 0; e < NEXP; ++e) lg[e] *= scale;
    int i0 = 0;
#pragma unroll
    for (int e = 1; e < NEXP; ++e) if (lg[e] > lg[i0]) i0 = e;   // first-occurrence max
    int i1 = (i0 == 0) ? 1 : 0;
#pragma unroll
    for (int e = 0; e < NEXP; ++e) if (e != i0 && lg[e] > lg[i1]) i1 = e;
    const float v0 = lg[i0], v1 = lg[i1];
    const float w0 = 1.f / (1.f + expf(v1 - v0));   // softmax over the 2 picked logits
    const float w1v = 1.f - w0;
    int s0 = atomicAdd(&counts[i0], 1);
    tok_id[i0 * NTOK + s0] = tok;
    tok_w[i0 * NTOK + s0] = w0;
    int s1 = atomicAdd(&counts[i1], 1);
    tok_id[i1 * NTOK + s1] = tok;
    tok_w[i1 * NTOK + s1] = w1v;
  }
}

// ---------------- Finalize: padded prefix offsets for compacted h ----------------
__global__ void finalize_kernel(const int* __restrict__ counts, int* __restrict__ hoff) {
  if (threadIdx.x == 0) {
    int off = 0;
    for (int e = 0; e < NEXP; ++e) { hoff[e] = off; off += ((counts[e] + TM - 1) / TM) * TM; }
  }
}

// ---------------- Stage A: h = silu(Xe@w1^T + b1) * (Xe@w2^T + b2) ----------------
__global__ __launch_bounds__(256, 2) void stagea_kernel(
    const float* __restrict__ x,
    const float* __restrict__ w1, const float* __restrict__ b1,
    const float* __restrict__ w2, const float* __restrict__ b2,
    const int* __restrict__ tok_id,
    const int* __restrict__ counts, const int* __restrict__ hoff,
    short* __restrict__ h)
{
  const int e = blockIdx.z;
  const int cnt = counts[e];
  const int mt = blockIdx.y;
  if (mt * TM >= cnt) return;
  const int nt = blockIdx.x;

  __shared__ __align__(16) short sA[TM * LDP];
  __shared__ __align__(16) short sB1[TN * LDP];
  __shared__ __align__(16) short sB2[TN * LDP];
  __shared__ int srow[TM];

  const int t = threadIdx.x;
  if (t < TM) {
    int id = tok_id[e * NTOK + mt * TM + t];
    srow[t] = id < 0 ? 0 : id;   // pad rows duplicate token 0; discarded in stage B
  }

  const float* wa = w1 + (size_t)e * HDIM * DDIM + (size_t)(nt * TN) * DDIM;
  const float* wb = w2 + (size_t)e * HDIM * DDIM + (size_t)(nt * TN) * DDIM;

  const int lane = t & 63;
  const int wv = t >> 6;
  const int wm = (wv >> 1) * 64;
  const int wn = (wv & 1) * 64;
  const int lr = lane & 15;
  const int lq = lane >> 4;

  f32x4 acc1[4][4] = {};
  f32x4 acc2[4][4] = {};

  const int r0 = t >> 4;   // staging row base
  const int c4 = t & 15;   // float4 column within row

  for (int k0 = 0; k0 < DDIM; k0 += BK) {
    __syncthreads();
#pragma unroll
    for (int j = 0; j < 8; ++j) {
      const int r = r0 + j * 16;
      const f32x4 v = *(const f32x4*)(x + (size_t)srow[r] * DDIM + k0 + c4 * 4);
      bf16x4 bv = { f2bf(v[0]), f2bf(v[1]), f2bf(v[2]), f2bf(v[3]) };
      *(bf16x4*)(sA + r * LDP + c4 * 4) = bv;
    }
#pragma unroll
    for (int j = 0; j < 8; ++j) {
      const int r = r0 + j * 16;
      const f32x4 v1 = *(const f32x4*)(wa + (size_t)r * DDIM + k0 + c4 * 4);
      bf16x4 b1v = { f2bf(v1[0]), f2bf(v1[1]), f2bf(v1[2]), f2bf(v1[3]) };
      *(bf16x4*)(sB1 + r * LDP + c4 * 4) = b1v;
      const f32x4 v2 = *(const f32x4*)(wb + (size_t)r * DDIM + k0 + c4 * 4);
      bf16x4 b2v = { f2bf(v2[0]), f2bf(v2[1]), f2bf(v2[2]), f2bf(v2[3]) };
      *(bf16x4*)(sB2 + r * LDP + c4 * 4) = b2v;
    }
    __syncthreads();
#pragma unroll
    for (int ks = 0; ks < BK; ks += 32) {
      bf16x8 af[4], bfa[4], bfb[4];
#pragma unroll
      for (int mi = 0; mi < 4; ++mi)
        af[mi] = *(const bf16x8*)(sA + (wm + mi * 16 + lr) * LDP + ks + lq * 8);
#pragma unroll
      for (int ni = 0; ni < 4; ++ni) {
        bfa[ni] = *(const bf16x8*)(sB1 + (wn + ni * 16 + lr) * LDP + ks + lq * 8);
        bfb[ni] = *(const bf16x8*)(sB2 + (wn + ni * 16 + lr) * LDP + ks + lq * 8);
      }
#pragma unroll
      for (int mi = 0; mi < 4; ++mi)
#pragma unroll
        for (int ni = 0; ni < 4; ++ni) {
          acc1[mi][ni] = __builtin_amdgcn_mfma_f32_16x16x32_bf16(af[mi], bfa[ni], acc1[mi][ni], 0, 0, 0);
          acc2[mi][ni] = __builtin_amdgcn_mfma_f32_16x16x32_bf16(af[mi], bfb[ni], acc2[mi][ni], 0, 0, 0);
        }
    }
  }

  const int hbase = hoff[e] + mt * TM;
#pragma unroll
  for (int ni = 0; ni < 4; ++ni) {
    const int col = nt * TN + wn + ni * 16 + lr;
    const float bb1 = b1[e * HDIM + col];
    const float bb2 = b2[e * HDIM + col];
#pragma unroll
    for (int mi = 0; mi < 4; ++mi) {
#pragma unroll
      for (int r = 0; r < 4; ++r) {
        const int row = wm + mi * 16 + lq * 4 + r;
        const float z1 = acc1[mi][ni][r] + bb1;
        const float z2 = acc2[mi][ni][r] + bb2;
        const float hv = (z1 / (1.f + expf(-z1))) * z2;
        h[(size_t)(hbase + row) * HDIM + col] = f2bf(hv);
      }
    }
  }
}

// ---------------- Stage B: y += weight * (h @ w3^T + b3), scatter by token ----------------
__global__ __launch_bounds__(256, 2) void stageb_kernel(
    const short* __restrict__ h,
    const float* __restrict__ w3, const float* __restrict__ b3,
    const int* __restrict__ tok_id, const float* __restrict__ tok_w,
    const int* __restrict__ counts, const int* __restrict__ hoff,
    float* __restrict__ y)
{
  const int e = blockIdx.z;
  const int cnt = counts[e];
  const int mt = blockIdx.y;
  if (mt * TM >= cnt) return;
  const int nt = blockIdx.x;

  __shared__ __align__(16) short sA[TM * LDP];
  __shared__ __align__(16) short sB[TN * LDP];

  const int t = threadIdx.x;
  const int lane = t & 63;
  const int wv = t >> 6;
  const int wm = (wv >> 1) * 64;
  const int wn = (wv & 1) * 64;
  const int lr = lane & 15;
  const int lq = lane >> 4;

  const short* hrow = h + (size_t)(hoff[e] + mt * TM) * HDIM;
  const float* wc = w3 + (size_t)e * DDIM * HDIM + (size_t)(nt * TN) * HDIM;

  f32x4 acc[4][4] = {};

  const int rA = t >> 3;   // h staging: 8 x bf16x8 slots per row
  const int c8 = t & 7;
  const int rB = t >> 4;
  const int c4 = t & 15;

  for (int k0 = 0; k0 < HDIM; k0 += BK) {
    __syncthreads();
#pragma unroll
    for (int j = 0; j < 4; ++j) {
      const int r = rA + j * 32;
      bf16x8 v = *(const bf16x8*)(hrow + (size_t)r * HDIM + k0 + c8 * 8);
      *(bf16x8*)(sA + r * LDP + c8 * 8) = v;
    }
#pragma unroll
    for (int j = 0; j < 8; ++j) {
      const int r = rB + j * 16;
      const f32x4 v = *(const f32x4*)(wc + (size_t)r * HDIM + k0 + c4 * 4);
      bf16x4 bv = { f2bf(v[0]), f2bf(v[1]), f2bf(v[2]), f2bf(v[3]) };
      *(bf16x4*)(sB + r * LDP + c4 * 4) = bv;
    }
    __syncthreads();
#pragma unroll
    for (int ks = 0; ks < BK; ks += 32) {
      bf16x8 af[4], bfr[4];
#pragma unroll
      for (int mi = 0; mi < 4; ++mi)
        af[mi] = *(const bf16x8*)(sA + (wm + mi * 16 + lr) * LDP + ks + lq * 8);
#pragma unroll
      for (int ni = 0; ni < 4; ++ni)
        bfr[ni] = *(const bf16x8*)(sB + (wn + ni * 16 + lr) * LDP + ks + lq * 8);
#pragma unroll
      for (int mi = 0; mi < 4; ++mi)
#pragma unroll
        for (int ni = 0; ni < 4; ++ni)
          acc[mi][ni] = __builtin_amdgcn_mfma_f32_16x16x32_bf16(af[mi], bfr[ni], acc[mi][ni], 0, 0, 0);
    }
  }

#pragma unroll
  for (int ni = 0; ni < 4; ++ni) {
    const int col = nt * TN + wn + ni * 16 + lr;
    const float bb3 = b3[e * DDIM + col];
#pragma unroll
    for (int mi = 0; mi < 4; ++mi) {
#pragma unroll
      for (int r = 0; r < 4; ++r) {
        const int row = mt * TM + wm + mi * 16 + lq * 4 + r;
        const int tok = tok_id[e * NTOK + row];
        if (tok >= 0) {
          const float wgt = tok_w[e * NTOK + row];
          atomicAdd(&y[(size_t)tok * DDIM + col], wgt * (acc[mi][ni][r] + bb3));
        }
      }
    }
  }
}

extern "C" void kernel_launch(void* const* d_in, const int* in_sizes, int n_in,
                              void* d_out, int out_size, void* d_ws, size_t ws_size,
                              hipStream_t stream) {
  const float* x  = (const float*)d_in[0];
  const float* gw = (const float*)d_in[1];
  const float* rs = (const float*)d_in[2];
  const float* w1 = (const float*)d_in[3];
  const float* b1 = (const float*)d_in[4];
  const float* w2 = (const float*)d_in[5];
  const float* b2 = (const float*)d_in[6];
  const float* w3 = (const float*)d_in[7];
  const float* b3 = (const float*)d_in[8];
  // d_in[9] = top_k (fixed 2)

  char* ws = (char*)d_ws;
  int*   tok_id = (int*)ws;                 // E*N ints      = 131072 B
  float* tok_w  = (float*)(ws + 131072);    // E*N floats    = 131072 B
  int*   counts = (int*)(ws + 262144);      // 8 ints
  int*   hoff   = (int*)(ws + 262176);      // 8 ints
  short* h      = (short*)(ws + 262656);    // <=9216 rows * 4096 bf16 = 75.5 MB

  hipMemsetAsync(counts, 0, 32, stream);
  hipMemsetAsync(tok_id, 0xFF, 131072, stream);   // pad token id = -1
  hipMemsetAsync(d_out, 0, (size_t)out_size * sizeof(float), stream);

  router_kernel<<<dim3(NTOK / 4), dim3(256), 0, stream>>>(x, gw, rs, tok_id, tok_w, counts);
  finalize_kernel<<<dim3(1), dim3(64), 0, stream>>>(counts, hoff);
  stagea_kernel<<<dim3(HDIM / TN, NTOK / TM, NEXP), dim3(256), 0, stream>>>(
      x, w1, b1, w2, b2, tok_id, counts, hoff, h);
  stageb_kernel<<<dim3(DDIM / TN, NTOK / TM, NEXP), dim3(256), 0, stream>>>(
      h, w3, b3, tok_id, tok_w, counts, hoff, (float*)d_out);
}